// Round 10
// baseline (352.878 us; speedup 1.0000x reference)
//
#include <hip/hip_runtime.h>

#define NE 50000
#define NN 10000
#define KH 96
#define KE 128          // padded K: 96 + bias row (=1*b2) + zeros
#define WN 6928
#define NTILE 484
#define IN_SZ 156
#define EPW 32          // edges per workgroup in tp_kernel

typedef __attribute__((ext_vector_type(8))) short short8;
typedef __attribute__((ext_vector_type(4))) float float4v;

__device__ __forceinline__ unsigned short f2bf(float x) {
  unsigned u = __float_as_uint(x);
  unsigned r = (u + 0x7FFFu + ((u >> 16) & 1u)) >> 16;   // RNE
  return (unsigned short)r;
}
__device__ __forceinline__ float b2f(unsigned short u) {
  return __uint_as_float(((unsigned)u) << 16);
}

// ---- forced-pipeline primitives (coalesced tile-major layout, r9-verified) ----
__device__ __forceinline__ void issue4(short8 (&B)[4], const unsigned short* p) {
  asm volatile("global_load_dwordx4 %0, %4, off\n\t"
               "global_load_dwordx4 %1, %4, off offset:1024\n\t"
               "global_load_dwordx4 %2, %4, off offset:2048\n\t"
               "global_load_dwordx4 %3, %4, off offset:3072"
               : "=&v"(B[0]), "=&v"(B[1]), "=&v"(B[2]), "=&v"(B[3])
               : "v"(p));
}
__device__ __forceinline__ void wait8(short8 (&B)[4]) {
  asm volatile("s_waitcnt vmcnt(8)"
               : "+v"(B[0]), "+v"(B[1]), "+v"(B[2]), "+v"(B[3]));
}
__device__ __forceinline__ void wait4(short8 (&B)[4]) {
  asm volatile("s_waitcnt vmcnt(4)"
               : "+v"(B[0]), "+v"(B[1]), "+v"(B[2]), "+v"(B[3]));
}
__device__ __forceinline__ void wait0(short8 (&B)[4]) {
  asm volatile("s_waitcnt vmcnt(0)"
               : "+v"(B[0]), "+v"(B[1]), "+v"(B[2]), "+v"(B[3]));
}

// ---------------- Kernel P (fused prep): W2PT + W1T + zero acc/icnt + h_ext row pad -------
// blocks [0,484): W2PT tile b; [484,520): W1T; [520,2054): zero acc+icnt; [2054]: h_ext pad.
__global__ __launch_bounds__(256) void prep_kernel(
    const float* __restrict__ W2, const float* __restrict__ b2,
    const float* __restrict__ W1,
    unsigned short* __restrict__ W2PT, unsigned short* __restrict__ W1T,
    uint4* __restrict__ zbase, unsigned short* __restrict__ h_ext)
{
  const int b = blockIdx.x, tid = threadIdx.x;
  if (b < NTILE) {
    // W2PT short index = t*2048 + s*512 + lane*8; lane=q*16+l holds
    // B[n=t*16+l][k=s*32+q*8..+8]; k=96 -> b2, k>96 -> 0.
    int lane = tid & 63, s = tid >> 6;
    int l = lane & 15, q = lane >> 4;
    int np = b * 16 + l;
    int c;
    if (np < 2784) c = np;
    else if (np < 3872) { int rel = np - 2784, i = rel >> 4, o = rel & 15; c = (o < 10) ? 2784 + i * 10 + o : -1; }
    else if (np < 4960) { int rel = np - 3872, i = rel >> 4, o = rel & 15; c = (o < 10) ? 3464 + i * 10 + o : -1; }
    else c = 4144 + (np - 4960);
    int kbase = s * 32 + q * 8;
    unsigned short o8[8];
    #pragma unroll
    for (int j = 0; j < 8; ++j) {
      int k = kbase + j;
      float v = 0.f;
      if (c >= 0) v = (k < KH) ? W2[(size_t)k * WN + c] : (k == KH ? b2[c] : 0.f);
      o8[j] = f2bf(v);
    }
    uint4 pk;
    pk.x = o8[0] | ((unsigned)o8[1] << 16);
    pk.y = o8[2] | ((unsigned)o8[3] << 16);
    pk.z = o8[4] | ((unsigned)o8[5] << 16);
    pk.w = o8[6] | ((unsigned)o8[7] << 16);
    *(uint4*)(W2PT + ((size_t)b * 256 + tid) * 8) = pk;
  } else if (b < NTILE + 36) {
    int j = (b - NTILE) * 256 + tid;            // 9216 exactly
    int c = j / KH, k = j - c * KH;
    W1T[c * KH + k] = f2bf(W1[k * KH + c]);
  } else if (b < NTILE + 36 + 1534) {
    int idx = (b - NTILE - 36) * 256 + tid;
    if (idx < 392500) zbase[idx] = (uint4){0u, 0u, 0u, 0u};   // acc (390000) + icnt (2500)
  } else {
    ((uint4*)(h_ext + (size_t)50000 * KE))[tid] = (uint4){0u, 0u, 0u, 0u};  // rows 50000..50015
  }
}

// ---------------- Kernel 1: h_ext via MFMA: relu(ea @ W1 + b1); inline f32->bf16 ----------
__global__ __launch_bounds__(384) void mlp1_kernel(
    const float* __restrict__ edge_attr, const unsigned short* __restrict__ W1T,
    const float* __restrict__ b1, unsigned short* __restrict__ h_ext)
{
  const int tid = threadIdx.x;
  const int e0 = blockIdx.x * 16;
  const int w = tid >> 6, l = tid & 15, q = (tid >> 4) & 3;

  short8 a[3], b[3];
  const float* ar = edge_attr + (size_t)(e0 + l) * KH + q * 8;
  #pragma unroll
  for (int s = 0; s < 3; ++s) {
    float4 x = *(const float4*)(ar + s * 32);
    float4 y = *(const float4*)(ar + s * 32 + 4);
    a[s][0] = (short)f2bf(x.x); a[s][1] = (short)f2bf(x.y);
    a[s][2] = (short)f2bf(x.z); a[s][3] = (short)f2bf(x.w);
    a[s][4] = (short)f2bf(y.x); a[s][5] = (short)f2bf(y.y);
    a[s][6] = (short)f2bf(y.z); a[s][7] = (short)f2bf(y.w);
    b[s] = *(const short8*)(W1T + (size_t)(w * 16 + l) * KH + s * 32 + q * 8);
  }
  float4v C = {0.f, 0.f, 0.f, 0.f};
  #pragma unroll
  for (int s = 0; s < 3; ++s)
    C = __builtin_amdgcn_mfma_f32_16x16x32_bf16(a[s], b[s], C, 0, 0, 0);

  float bv = b1[w * 16 + l];
  #pragma unroll
  for (int r = 0; r < 4; ++r)
    h_ext[(size_t)(e0 + q * 4 + r) * KE + w * 16 + l] = f2bf(fmaxf(C[r] + bv, 0.f));

  for (int idx = tid; idx < 16 * 32; idx += 384) {   // pad cols 96..127
    int e = idx >> 5, c = 96 + (idx & 31);
    h_ext[(size_t)(e0 + e) * KE + c] = (c == 96) ? (unsigned short)0x3F80 : (unsigned short)0;
  }
}

// ---------------- Kernel 2: MFMA w-GEMM fused with TP; 3-deep coalesced B pipeline --------
__global__ __launch_bounds__(512, 2) void tp_kernel(
    const unsigned short* __restrict__ h_ext, const float* __restrict__ node_attr,
    const int* __restrict__ edge_index, const float* __restrict__ edge_sh,
    const unsigned short* __restrict__ W2PT,
    float* __restrict__ acc, int* __restrict__ icnt)
{
  __shared__ unsigned short sIn[EPW][160];         // bf16 gathered node_attr
  __shared__ float sOut[EPW][160];                 // f32 output staging
  __shared__ float sF0[2][60][EPW];                // scalar feats f32 [fam][i][e] (pads 58,59)
  __shared__ unsigned short sF1[2][72][3][EPW];    // vector feats bf16 [fam][i][cc][e] (pads 68..71)
  __shared__ float sShs[EPW][4];
  __shared__ int sSrc[EPW], sDst[EPW];

  const int tid = threadIdx.x;
  const int e0 = blockIdx.x * EPW;

  if (tid < EPW) {
    int ok = (e0 + tid) < NE;
    int s = ok ? edge_index[e0 + tid] : 0;
    int d = ok ? edge_index[NE + e0 + tid] : 0;
    sSrc[tid] = s; sDst[tid] = d;
    if (ok) atomicAdd(&icnt[s], 1);
  }
  if (tid >= 128 && tid < 256) {
    int t2 = tid - 128;
    int e = t2 >> 2, c = t2 & 3;
    sShs[e][c] = ((e0 + e) < NE) ? edge_sh[(size_t)(e0 + e) * 4 + c] : 0.f;
  }
  __syncthreads();

  // vectorized gather: 32 rows x 39 float4
  for (int idx = tid; idx < EPW * 39; idx += 512) {
    int e = idx / 39, f4 = idx - e * 39;
    float4 x = *(const float4*)(node_attr + (size_t)sDst[e] * IN_SZ + f4 * 4);
    ushort4 u;
    u.x = f2bf(x.x); u.y = f2bf(x.y); u.z = f2bf(x.z); u.w = f2bf(x.w);
    *(ushort4*)&sIn[e][f4 * 4] = u;
  }
  for (int idx = tid; idx < EPW * 160; idx += 512) (&sOut[0][0])[idx] = 0.f;
  __syncthreads();

  { // ---- feature construction: 16 workers per edge ----
    const int e = tid >> 4, j = tid & 15;
    const float sh0 = sShs[e][0], sx = sShs[e][1], sy = sShs[e][2], sz = sShs[e][3];
    const float i3 = 0.57735026918962576f, i2 = 0.70710678118654752f;
    for (int i = j; i < 48; i += 16) {
      float v0 = b2f(sIn[e][i]), w0 = b2f(sIn[e][108 + i]);
      sF0[0][i][e] = v0 * sh0;
      sF0[1][10 + i][e] = w0 * sh0;
      sF1[0][i][0][e] = f2bf(v0 * sx); sF1[0][i][1][e] = f2bf(v0 * sy); sF1[0][i][2][e] = f2bf(v0 * sz);
      sF1[1][20 + i][0][e] = f2bf(w0 * sx); sF1[1][20 + i][1][e] = f2bf(w0 * sy); sF1[1][20 + i][2][e] = f2bf(w0 * sz);
    }
    if (j < 10) {
      const int v = j;
      float ax = b2f(sIn[e][48 + 3 * v]), ay = b2f(sIn[e][48 + 3 * v + 1]), az = b2f(sIn[e][48 + 3 * v + 2]);
      float bx = b2f(sIn[e][78 + 3 * v]), by = b2f(sIn[e][78 + 3 * v + 1]), bz = b2f(sIn[e][78 + 3 * v + 2]);
      sF0[0][48 + v][e] = (ax * sx + ay * sy + az * sz) * i3;
      sF0[1][v][e]      = (bx * sx + by * sy + bz * sz) * i3;
      sF1[0][48 + v][0][e] = f2bf(ax * sh0); sF1[0][48 + v][1][e] = f2bf(ay * sh0); sF1[0][48 + v][2][e] = f2bf(az * sh0);
      sF1[0][58 + v][0][e] = f2bf((by * sz - bz * sy) * i2);
      sF1[0][58 + v][1][e] = f2bf((bz * sx - bx * sz) * i2);
      sF1[0][58 + v][2][e] = f2bf((bx * sy - by * sx) * i2);
      sF1[1][v][0][e] = f2bf((ay * sz - az * sy) * i2);
      sF1[1][v][1][e] = f2bf((az * sx - ax * sz) * i2);
      sF1[1][v][2][e] = f2bf((ax * sy - ay * sx) * i2);
      sF1[1][10 + v][0][e] = f2bf(bx * sh0); sF1[1][10 + v][1][e] = f2bf(by * sh0); sF1[1][10 + v][2][e] = f2bf(bz * sh0);
    }
  }
  // zero pad rows (sF0 i=58,59; sF1 i=68..71)
  if (tid < 128) {
    int fam = tid >> 6, i = 58 + ((tid >> 5) & 1), e = tid & 31;
    sF0[fam][i][e] = 0.f;
  }
  for (int idx = tid; idx < 768; idx += 512) {
    int fam = idx / 384, r = idx - fam * 384;
    int i = 68 + r / 96, r2 = r % 96, cc = r2 >> 5, e = r2 & 31;
    sF1[fam][i][cc][e] = 0;
  }
  __syncthreads();

  const int wv = tid >> 6, l = tid & 15, q = (tid >> 4) & 3;

  short8 Af[2][4];
  #pragma unroll
  for (int m = 0; m < 2; ++m) {
    const unsigned short* ar = h_ext + (size_t)(e0 + m * 16 + l) * KE + q * 8;
    #pragma unroll
    for (int s = 0; s < 4; ++s) Af[m][s] = *(const short8*)(ar + s * 32);
  }

  const unsigned short* wlane = W2PT + (size_t)(tid & 63) * 8;   // coalesced: lane*16B
  short8 Ba[4], Bb[4], Bc[4];

  if (wv < 4) {
    // ---------------- scalar families (0e / 0o), 3 ob-phases x 30 iters ----------------
    const int sf = wv >> 1;
    const int ibeg = (wv & 1) * 30;
    const int tb = sf ? 310 : 0;
    const int obase = sf ? 108 : 0;
    #pragma unroll 1
    for (int ob = 0; ob < 3; ++ob) {
      float a0[4] = {0.f, 0.f, 0.f, 0.f}, a1[4] = {0.f, 0.f, 0.f, 0.f};
      auto addr = [&](int ii) {
        int i = ibeg + ii; if (i >= 58) i = ibeg;          // pad iters load a safe tile
        return wlane + (size_t)(tb + 3 * i + ob) * 2048;
      };
      auto body = [&](const short8 (&B)[4], int ii) {
        int i = ibeg + ii;
        float4 f0 = *(const float4*)&sF0[sf][i][q * 4];
        float4 f1 = *(const float4*)&sF0[sf][i][16 + q * 4];
        float4v C0 = {0.f, 0.f, 0.f, 0.f}, C1 = {0.f, 0.f, 0.f, 0.f};
        #pragma unroll
        for (int s = 0; s < 4; ++s) {
          C0 = __builtin_amdgcn_mfma_f32_16x16x32_bf16(Af[0][s], B[s], C0, 0, 0, 0);
          C1 = __builtin_amdgcn_mfma_f32_16x16x32_bf16(Af[1][s], B[s], C1, 0, 0, 0);
        }
        a0[0] += C0[0] * f0.x; a0[1] += C0[1] * f0.y; a0[2] += C0[2] * f0.z; a0[3] += C0[3] * f0.w;
        a1[0] += C1[0] * f1.x; a1[1] += C1[1] * f1.y; a1[2] += C1[2] * f1.z; a1[3] += C1[3] * f1.w;
      };
      issue4(Ba, addr(0)); issue4(Bb, addr(1)); issue4(Bc, addr(2));
      #pragma unroll 1
      for (int ii = 0; ii < 27; ii += 3) {
        wait8(Ba); body(Ba, ii);     issue4(Ba, addr(ii + 3));
        wait8(Bb); body(Bb, ii + 1); issue4(Bb, addr(ii + 4));
        wait8(Bc); body(Bc, ii + 2); issue4(Bc, addr(ii + 5));
      }
      wait8(Ba); body(Ba, 27);
      wait4(Bb); body(Bb, 28);
      wait0(Bc); body(Bc, 29);
      const int col = obase + ob * 16 + l;
      #pragma unroll
      for (int r = 0; r < 4; ++r) {
        unsafeAtomicAdd(&sOut[q * 4 + r][col], a0[r]);
        unsafeAtomicAdd(&sOut[16 + q * 4 + r][col], a1[r]);
      }
    }
  } else {
    // ---------------- vector families (1o / 1e), 36/36 i-halves (i padded to 72) ----------
    const int vf = (wv >> 1) - 2;
    const int ibeg = (wv & 1) * 36;
    const int tb = vf ? 242 : 174;
    float r0[4][3] = {{0.f}}, r1[4][3] = {{0.f}};
    auto addr = [&](int ii) {
      int i = ibeg + ii; if (i >= 68) i = ibeg;
      return wlane + (size_t)(tb + i) * 2048;
    };
    auto body = [&](const short8 (&B)[4], int ii) {
      int i = ibeg + ii;
      ushort4 g0[3], g1[3];
      #pragma unroll
      for (int cc = 0; cc < 3; ++cc) {
        g0[cc] = *(const ushort4*)&sF1[vf][i][cc][q * 4];
        g1[cc] = *(const ushort4*)&sF1[vf][i][cc][16 + q * 4];
      }
      float4v C0 = {0.f, 0.f, 0.f, 0.f}, C1 = {0.f, 0.f, 0.f, 0.f};
      #pragma unroll
      for (int s = 0; s < 4; ++s) {
        C0 = __builtin_amdgcn_mfma_f32_16x16x32_bf16(Af[0][s], B[s], C0, 0, 0, 0);
        C1 = __builtin_amdgcn_mfma_f32_16x16x32_bf16(Af[1][s], B[s], C1, 0, 0, 0);
      }
      #pragma unroll
      for (int cc = 0; cc < 3; ++cc) {
        r0[0][cc] += C0[0] * b2f(g0[cc].x); r0[1][cc] += C0[1] * b2f(g0[cc].y);
        r0[2][cc] += C0[2] * b2f(g0[cc].z); r0[3][cc] += C0[3] * b2f(g0[cc].w);
        r1[0][cc] += C1[0] * b2f(g1[cc].x); r1[1][cc] += C1[1] * b2f(g1[cc].y);
        r1[2][cc] += C1[2] * b2f(g1[cc].z); r1[3][cc] += C1[3] * b2f(g1[cc].w);
      }
    };
    issue4(Ba, addr(0)); issue4(Bb, addr(1)); issue4(Bc, addr(2));
    #pragma unroll 1
    for (int ii = 0; ii < 33; ii += 3) {
      wait8(Ba); body(Ba, ii);     issue4(Ba, addr(ii + 3));
      wait8(Bb); body(Bb, ii + 1); issue4(Bb, addr(ii + 4));
      wait8(Bc); body(Bc, ii + 2); issue4(Bc, addr(ii + 5));
    }
    wait8(Ba); body(Ba, 33);
    wait4(Bb); body(Bb, 34);
    wait0(Bc); body(Bc, 35);
    if (l < 10) {
      const int col = (vf ? 78 : 48) + 3 * l;
      #pragma unroll
      for (int r = 0; r < 4; ++r)
        #pragma unroll
        for (int cc = 0; cc < 3; ++cc) {
          unsafeAtomicAdd(&sOut[q * 4 + r][col + cc], r0[r][cc]);
          unsafeAtomicAdd(&sOut[16 + q * 4 + r][col + cc], r1[r][cc]);
        }
    }
  }
  __syncthreads();

  // ---- scatter to global ----
  const float n58 = 0.13130643285972254f, n68 = 0.12126781251816650f;
  for (int idx = tid; idx < EPW * IN_SZ; idx += 512) {
    int e = idx / IN_SZ, o = idx - e * IN_SZ;
    if (e0 + e < NE) {
      float nrm = (o < 48 || o >= 108) ? n58 : n68;
      unsafeAtomicAdd(&acc[(size_t)sSrc[e] * IN_SZ + o], sOut[e][o] * nrm);
    }
  }
}

// ---------------- Kernel 3: out = acc / max(cnt,1) + node_attr ----------------
__global__ __launch_bounds__(256) void finalize_kernel(
    const float* __restrict__ acc, const int* __restrict__ icnt,
    const float* __restrict__ node_attr, float* __restrict__ out)
{
  int idx = blockIdx.x * 256 + threadIdx.x;
  if (idx < NN * IN_SZ) {
    int n = idx / IN_SZ;
    out[idx] = acc[idx] / fmaxf((float)icnt[n], 1.f) + node_attr[idx];
  }
}

extern "C" void kernel_launch(void* const* d_in, const int* in_sizes, int n_in,
                              void* d_out, int out_size, void* d_ws, size_t ws_size,
                              hipStream_t stream)
{
  const float* node_attr  = (const float*)d_in[0];
  const int*   edge_index = (const int*)d_in[1];
  const float* edge_attr  = (const float*)d_in[2];
  const float* edge_sh    = (const float*)d_in[3];
  const float* W1 = (const float*)d_in[4];
  const float* b1 = (const float*)d_in[5];
  const float* W2 = (const float*)d_in[6];
  const float* b2 = (const float*)d_in[7];
  float* out = (float*)d_out;

  // flat layout, no aliasing (ea_bf eliminated): ~21.1 MB total
  unsigned short* h_ext = (unsigned short*)d_ws;              // 50016 * 128 bf16
  unsigned short* W2PT  = h_ext + (size_t)50016 * KE;         // 484 * 2048 bf16
  unsigned short* W1T   = W2PT + (size_t)NTILE * 2048;        // 9216 bf16
  float* acc  = (float*)(W1T + 9216);                         // 10000*156 f32 (16B aligned)
  int*   icnt = (int*)(acc + (size_t)NN * IN_SZ);             // 10000 i32, contiguous after acc

  prep_kernel<<<NTILE + 36 + 1534 + 1, 256, 0, stream>>>(W2, b2, W1, W2PT, W1T,
                                                         (uint4*)acc, h_ext);
  mlp1_kernel<<<NE / 16, 384, 0, stream>>>(edge_attr, W1T, b1, h_ext);
  tp_kernel<<<(NE + EPW - 1) / EPW, 512, 0, stream>>>(h_ext, node_attr, edge_index,
                                                      edge_sh, W2PT, acc, icnt);
  finalize_kernel<<<(NN * IN_SZ + 255) / 256, 256, 0, stream>>>(acc, icnt, node_attr, out);
}